// Round 1
// baseline (96.756 us; speedup 1.0000x reference)
//
#include <hip/hip_runtime.h>

#define BB 2
#define SS 2048
#define DD 1024
#define INNER 1024
#define NCHUNK 64
#define ROWS_PER_CHUNK (SS / NCHUNK)  // 32

// K1: hbar[b,d] = sum_s hidden[b,s,d]  (atomic partial sums over 64 row-chunks)
__global__ void colsum_kernel(const float* __restrict__ h, float* __restrict__ hbar) {
    int b = blockIdx.x / NCHUNK;
    int chunk = blockIdx.x % NCHUNK;
    int t = threadIdx.x;  // 0..255, each owns 4 consecutive d (float4)
    const float4* hp = reinterpret_cast<const float4*>(h + (size_t)b * SS * DD);
    float4 acc = make_float4(0.f, 0.f, 0.f, 0.f);
    int s0 = chunk * ROWS_PER_CHUNK;
    #pragma unroll 4
    for (int s = s0; s < s0 + ROWS_PER_CHUNK; ++s) {
        float4 v = hp[(size_t)s * (DD / 4) + t];
        acc.x += v.x; acc.y += v.y; acc.z += v.z; acc.w += v.w;
    }
    float* dst = hbar + b * DD + t * 4;
    atomicAdd(dst + 0, acc.x);
    atomicAdd(dst + 1, acc.y);
    atomicAdd(dst + 2, acc.z);
    atomicAdd(dst + 3, acc.w);
}

// K2/K3: y[b*INNER + i] = scale * dot(W[i, :], x[b, :])   (W is [1024,1024] row-major)
// one 64-lane wave per output; 512 blocks x 256 threads = 2048 waves = B*INNER outputs
__global__ void matvec_kernel(const float* __restrict__ W, const float* __restrict__ x,
                              float* __restrict__ y, float scale) {
    int wave = (blockIdx.x * blockDim.x + threadIdx.x) >> 6;  // 0..2047
    int lane = threadIdx.x & 63;
    int b = wave / INNER;
    int i = wave % INNER;
    const float4* Wp = reinterpret_cast<const float4*>(W + (size_t)i * 1024);
    const float4* xp = reinterpret_cast<const float4*>(x + b * 1024);
    float sum = 0.f;
    #pragma unroll
    for (int k4 = lane; k4 < 256; k4 += 64) {
        float4 w = Wp[k4];
        float4 xv = xp[k4];
        sum += w.x * xv.x + w.y * xv.y + w.z * xv.z + w.w * xv.w;
    }
    #pragma unroll
    for (int off = 32; off > 0; off >>= 1) sum += __shfl_down(sum, off);
    if (lane == 0) y[wave] = sum * scale;
}

// K4: out[b,s,:] = orow[b,:]
__global__ void bcast_kernel(const float* __restrict__ row, float* __restrict__ out) {
    const float4* r4 = reinterpret_cast<const float4*>(row);
    float4* o4 = reinterpret_cast<float4*>(out);
    const int total4 = BB * SS * (DD / 4);  // 1,048,576
    for (int i = blockIdx.x * blockDim.x + threadIdx.x; i < total4;
         i += gridDim.x * blockDim.x) {
        int d4 = i & (DD / 4 - 1);      // i % 256
        int b = i >> 19;                // i / (SS*DD/4) = i / 524288
        o4[i] = r4[b * (DD / 4) + d4];
    }
}

extern "C" void kernel_launch(void* const* d_in, const int* in_sizes, int n_in,
                              void* d_out, int out_size, void* d_ws, size_t ws_size,
                              hipStream_t stream) {
    const float* h  = (const float*)d_in[0];   // hidden_states [2,2048,1024]
    const float* Wv = (const float*)d_in[3];   // [1024,1024]
    const float* Wo = (const float*)d_in[4];   // [1024,1024]
    float* out = (float*)d_out;                // [2,2048,1024]

    float* hbar  = (float*)d_ws;               // 2048 floats
    float* vmean = hbar + BB * DD;             // 2048 floats
    float* orow  = vmean + BB * INNER;         // 2048 floats

    hipMemsetAsync(hbar, 0, BB * DD * sizeof(float), stream);
    colsum_kernel<<<BB * NCHUNK, 256, 0, stream>>>(h, hbar);
    matvec_kernel<<<512, 256, 0, stream>>>(Wv, hbar, vmean, 1.0f / (float)SS);
    matvec_kernel<<<512, 256, 0, stream>>>(Wo, vmean, orow, 1.0f);
    bcast_kernel<<<2048, 256, 0, stream>>>(orow, out);
}